// Round 1
// baseline (227.816 us; speedup 1.0000x reference)
//
#include <hip/hip_runtime.h>
#include <cstdint>
#include <cstddef>

// ---------------------------------------------------------------------------
// MultiHeadAttention: B=2 T=2048 C=1024 H=16 D=64, fp32 in/out, bf16 compute.
// Pipeline: cvt(x) -> transpose-cvt(Wq,Wk,Wv,Wproj) -> QKV GEMM (m97-style)
//           -> flash attention (causal, online softmax) -> proj GEMM + bias.
// ---------------------------------------------------------------------------

typedef __bf16 bf16;
typedef __attribute__((ext_vector_type(4))) __bf16 bf16x4;
typedef __attribute__((ext_vector_type(8))) __bf16 bf16x8;
typedef __attribute__((ext_vector_type(4))) float f32x4;

#define AS1 __attribute__((address_space(1)))
#define AS3 __attribute__((address_space(3)))
typedef const AS1 void* gptr_t;
typedef AS3 void* lptr_t;

static constexpr int Bb = 2, Tt = 2048, Cc = 1024, Hh = 16, Dd = 64;
static constexpr int Mtot = Bb * Tt;   // 4096 rows (b*T+t)
static constexpr int Ktot = Cc;        // 1024
static constexpr int Ntot = Hh * Dd;   // 1024

// ---------------- fp32 -> bf16 elementwise convert -------------------------
__global__ void cvt_f32_bf16(const float* __restrict__ in, bf16* __restrict__ out, int n) {
  int i = (blockIdx.x * blockDim.x + threadIdx.x) * 4;
  if (i >= n) return;
  const float4 v = *reinterpret_cast<const float4*>(in + i);
  bf16x4 o;
  o[0] = (bf16)v.x; o[1] = (bf16)v.y; o[2] = (bf16)v.z; o[3] = (bf16)v.w;
  *reinterpret_cast<bf16x4*>(out + i) = o;
}

// ------------- batched [R][S] f32 -> [S][R] bf16 transpose -----------------
__global__ void transpose_cvt(const float* __restrict__ in, bf16* __restrict__ out,
                              int R, int S) {
  __shared__ float tile[32][33];
  const int batch = blockIdx.z;
  in  += (size_t)batch * R * S;
  out += (size_t)batch * R * S;
  const int r0 = blockIdx.y * 32, s0 = blockIdx.x * 32;
  const int tx = threadIdx.x, ty = threadIdx.y;   // 32 x 8
#pragma unroll
  for (int i = 0; i < 32; i += 8) {
    int r = r0 + ty + i, s = s0 + tx;
    tile[ty + i][tx] = (r < R && s < S) ? in[(size_t)r * S + s] : 0.f;
  }
  __syncthreads();
#pragma unroll
  for (int i = 0; i < 32; i += 8) {
    int s = s0 + ty + i, r = r0 + tx;
    if (s < S && r < R) out[(size_t)s * R + r] = (bf16)tile[tx][ty + i];
  }
}

// ---------------- 128x128 GEMM mainloop (m97 structure) --------------------
// C[m0..+128][n0..+128] += A[M][K] (row-major bf16) x Bt[N][K] (row-major bf16)
// BK=64, global_load_lds width16, XOR-swizzled LDS (chunk j ^= row&7).
__device__ __forceinline__ void gemm_core_128(const bf16* __restrict__ A,
                                              const bf16* __restrict__ Bt,
                                              int m0, int n0, f32x4 acc[4][4]) {
  __shared__ __align__(16) char AsB[128 * 64 * 2];
  __shared__ __align__(16) char BsB[128 * 64 * 2];
  const int tid  = threadIdx.x;
  const int lane = tid & 63;
  const int w    = tid >> 6;
  const int li   = lane & 15, lg = lane >> 4;
  const int wr   = (w >> 1) * 64, wc = (w & 1) * 64;

  for (int kt = 0; kt < Ktot / 64; ++kt) {
    if (kt) __syncthreads();
    // stage 128x64 bf16 tiles of A and Bt; LDS dest linear, global src
    // pre-swizzled so swizzled reads land on conflict-free banks (G21).
#pragma unroll
    for (int it = 0; it < 4; ++it) {
      const int c   = it * 256 + tid;        // chunk id 0..1023 (16B chunks)
      const int row = c >> 3, j = c & 7;
      const int jsw = j ^ (row & 7);
      const bf16* ga = A  + (size_t)(m0 + row) * Ktot + kt * 64 + jsw * 8;
      const bf16* gb = Bt + (size_t)(n0 + row) * Ktot + kt * 64 + jsw * 8;
      __builtin_amdgcn_global_load_lds(gptr_t(ga), lptr_t(AsB + (it * 256 + w * 64) * 16), 16, 0, 0);
      __builtin_amdgcn_global_load_lds(gptr_t(gb), lptr_t(BsB + (it * 256 + w * 64) * 16), 16, 0, 0);
    }
    __syncthreads();
#pragma unroll
    for (int kk = 0; kk < 2; ++kk) {
      bf16x8 af[4], bfv[4];
#pragma unroll
      for (int mi = 0; mi < 4; ++mi) {
        const int row = wr + mi * 16 + li;
        const int jj  = (kk * 4 + lg) ^ (row & 7);
        af[mi] = *reinterpret_cast<const bf16x8*>(AsB + row * 128 + jj * 16);
      }
#pragma unroll
      for (int ni = 0; ni < 4; ++ni) {
        const int row = wc + ni * 16 + li;
        const int jj  = (kk * 4 + lg) ^ (row & 7);
        bfv[ni] = *reinterpret_cast<const bf16x8*>(BsB + row * 128 + jj * 16);
      }
#pragma unroll
      for (int mi = 0; mi < 4; ++mi)
#pragma unroll
        for (int ni = 0; ni < 4; ++ni)
          acc[mi][ni] = __builtin_amdgcn_mfma_f32_16x16x32_bf16(af[mi], bfv[ni], acc[mi][ni], 0, 0, 0);
    }
  }
}

// ---------------- QKV projection GEMM --------------------------------------
// z=0 -> q [B,H,T,D], z=1 -> k [B,H,T,D], z=2 -> v stored TRANSPOSED [B,H,D,T]
__global__ __launch_bounds__(256) void qkv_gemm(const bf16* __restrict__ xb,
    const bf16* __restrict__ wqt, const bf16* __restrict__ wkt, const bf16* __restrict__ wvt,
    bf16* __restrict__ q, bf16* __restrict__ k, bf16* __restrict__ vt) {
  const int m0 = blockIdx.y * 128, n0 = blockIdx.x * 128;
  const int z  = blockIdx.z;
  const bf16* Bt = (z == 0) ? wqt : (z == 1) ? wkt : wvt;
  bf16* outp     = (z == 0) ? q   : (z == 1) ? k   : vt;

  f32x4 acc[4][4];
#pragma unroll
  for (int mi = 0; mi < 4; ++mi)
#pragma unroll
    for (int ni = 0; ni < 4; ++ni) acc[mi][ni] = f32x4{0.f, 0.f, 0.f, 0.f};

  gemm_core_128(xb, Bt, m0, n0, acc);

  const int lane = threadIdx.x & 63, w = threadIdx.x >> 6;
  const int li = lane & 15, lg = lane >> 4;
  const int wr = (w >> 1) * 64, wc = (w & 1) * 64;
#pragma unroll
  for (int mi = 0; mi < 4; ++mi)
#pragma unroll
    for (int ni = 0; ni < 4; ++ni)
#pragma unroll
      for (int r = 0; r < 4; ++r) {
        const int m = m0 + wr + mi * 16 + lg * 4 + r;   // b*T + t
        const int n = n0 + wc + ni * 16 + li;           // h*64 + d
        const int b = m >> 11, tt = m & 2047;
        const int h = n >> 6,  d  = n & 63;
        const float v = acc[mi][ni][r];
        if (z < 2) outp[(((size_t)(b * Hh + h)) * Tt + tt) * Dd + d] = (bf16)v;
        else       outp[(((size_t)(b * Hh + h)) * Dd + d) * Tt + tt] = (bf16)v;
      }
}

// ---------------- output projection GEMM (+bias, f32 out) ------------------
__global__ __launch_bounds__(256) void proj_gemm(const bf16* __restrict__ attnb,
    const bf16* __restrict__ wpt, float* __restrict__ out, const float* __restrict__ bias) {
  const int m0 = blockIdx.y * 128, n0 = blockIdx.x * 128;
  f32x4 acc[4][4];
#pragma unroll
  for (int mi = 0; mi < 4; ++mi)
#pragma unroll
    for (int ni = 0; ni < 4; ++ni) acc[mi][ni] = f32x4{0.f, 0.f, 0.f, 0.f};

  gemm_core_128(attnb, wpt, m0, n0, acc);

  const int lane = threadIdx.x & 63, w = threadIdx.x >> 6;
  const int li = lane & 15, lg = lane >> 4;
  const int wr = (w >> 1) * 64, wc = (w & 1) * 64;
#pragma unroll
  for (int mi = 0; mi < 4; ++mi)
#pragma unroll
    for (int ni = 0; ni < 4; ++ni)
#pragma unroll
      for (int r = 0; r < 4; ++r) {
        const int m = m0 + wr + mi * 16 + lg * 4 + r;
        const int n = n0 + wc + ni * 16 + li;
        out[(size_t)m * Ntot + n] = acc[mi][ni][r] + bias[n];
      }
}

// ---------------- flash attention (causal) ---------------------------------
// grid (T/128, B*H); 4 waves/block, each wave owns 32 q-rows, s-tiles of 32.
// q,k: [B,H,T,D] bf16; vt: [B,H,D,T] bf16; out: [B,T,H*D] bf16.
__global__ __launch_bounds__(256) void attn_kernel(const bf16* __restrict__ Q,
    const bf16* __restrict__ K, const bf16* __restrict__ Vt, bf16* __restrict__ O) {
  const int tid = threadIdx.x, lane = tid & 63, w = tid >> 6;
  const int li = lane & 15, lg = lane >> 4;
  const int bh  = blockIdx.y;
  const int qt  = (int)gridDim.x - 1 - (int)blockIdx.x;  // heavy tiles first
  const int qr0 = qt * 128 + w * 32;

  const bf16* Qh = Q  + (size_t)bh * Tt * Dd;
  const bf16* Kh = K  + (size_t)bh * Tt * Dd;
  const bf16* Vh = Vt + (size_t)bh * Dd * Tt;

  __shared__ __align__(16) bf16 p_lds[4][32][40];   // +8 col pad: 80B row stride
  bf16 (*pl)[40] = p_lds[w];

  // Q fragments, resident for the whole s-loop
  bf16x8 aq[2][2];
#pragma unroll
  for (int mi = 0; mi < 2; ++mi)
#pragma unroll
    for (int kk = 0; kk < 2; ++kk)
      aq[mi][kk] = *reinterpret_cast<const bf16x8*>(Qh + (size_t)(qr0 + mi * 16 + li) * Dd + kk * 32 + lg * 8);

  f32x4 o[2][4];
  float mrun[2][4], lrun[2][4];
#pragma unroll
  for (int mi = 0; mi < 2; ++mi) {
#pragma unroll
    for (int ni = 0; ni < 4; ++ni) o[mi][ni] = f32x4{0.f, 0.f, 0.f, 0.f};
#pragma unroll
    for (int r = 0; r < 4; ++r) { mrun[mi][r] = -1e30f; lrun[mi][r] = 0.f; }
  }

  const float SCL = 0.125f * 1.44269504088896340736f;  // 1/sqrt(D) * log2(e)
  const int nsteps = (qr0 >> 5) + 1;

  for (int st = 0; st < nsteps; ++st) {
    const int s0 = st * 32;
    // K fragments (L2/L3-resident; no LDS staging — Common-mistake #7)
    bf16x8 bk[2][2];
#pragma unroll
    for (int ni = 0; ni < 2; ++ni)
#pragma unroll
      for (int kk = 0; kk < 2; ++kk)
        bk[ni][kk] = *reinterpret_cast<const bf16x8*>(Kh + (size_t)(s0 + ni * 16 + li) * Dd + kk * 32 + lg * 8);

    // S = Q K^T (scaled into log2 domain)
    f32x4 s[2][2];
#pragma unroll
    for (int mi = 0; mi < 2; ++mi)
#pragma unroll
      for (int ni = 0; ni < 2; ++ni) {
        s[mi][ni] = f32x4{0.f, 0.f, 0.f, 0.f};
#pragma unroll
        for (int kk = 0; kk < 2; ++kk)
          s[mi][ni] = __builtin_amdgcn_mfma_f32_16x16x32_bf16(aq[mi][kk], bk[ni][kk], s[mi][ni], 0, 0, 0);
      }

    const bool maskit = (st == nsteps - 1);   // only diagonal tile is partial
#pragma unroll
    for (int mi = 0; mi < 2; ++mi)
#pragma unroll
      for (int ni = 0; ni < 2; ++ni)
#pragma unroll
        for (int r = 0; r < 4; ++r) {
          float v = s[mi][ni][r] * SCL;
          if (maskit && (s0 + ni * 16 + li) > (qr0 + mi * 16 + lg * 4 + r)) v = -1e30f;
          s[mi][ni][r] = v;
        }

    // wave-parallel row max over 32 cols: pairwise + 16-lane butterfly
    float rmax[2][4], fac[2][4], rsum[2][4];
#pragma unroll
    for (int mi = 0; mi < 2; ++mi)
#pragma unroll
      for (int r = 0; r < 4; ++r) {
        float v = fmaxf(s[mi][0][r], s[mi][1][r]);
#pragma unroll
        for (int dlt = 1; dlt < 16; dlt <<= 1) v = fmaxf(v, __shfl_xor(v, dlt, 64));
        rmax[mi][r] = v;
        const float mn = fmaxf(mrun[mi][r], v);
        fac[mi][r]  = exp2f(mrun[mi][r] - mn);
        mrun[mi][r] = mn;
        rsum[mi][r] = 0.f;
      }

    // P = exp2(S - m), row sums
#pragma unroll
    for (int mi = 0; mi < 2; ++mi)
#pragma unroll
      for (int ni = 0; ni < 2; ++ni)
#pragma unroll
        for (int r = 0; r < 4; ++r) {
          const float p = exp2f(s[mi][ni][r] - mrun[mi][r]);
          s[mi][ni][r] = p;
          rsum[mi][r] += p;
        }
#pragma unroll
    for (int mi = 0; mi < 2; ++mi)
#pragma unroll
      for (int r = 0; r < 4; ++r) {
        float v = rsum[mi][r];
#pragma unroll
        for (int dlt = 1; dlt < 16; dlt <<= 1) v += __shfl_xor(v, dlt, 64);
        lrun[mi][r] = lrun[mi][r] * fac[mi][r] + v;
      }

    // rescale O, round-trip P through wave-private LDS into A-fragment layout
#pragma unroll
    for (int mi = 0; mi < 2; ++mi)
#pragma unroll
      for (int ni = 0; ni < 4; ++ni)
#pragma unroll
        for (int r = 0; r < 4; ++r) o[mi][ni][r] *= fac[mi][r];

#pragma unroll
    for (int mi = 0; mi < 2; ++mi)
#pragma unroll
      for (int ni = 0; ni < 2; ++ni)
#pragma unroll
        for (int r = 0; r < 4; ++r)
          pl[mi * 16 + lg * 4 + r][ni * 16 + li] = (bf16)s[mi][ni][r];

    bf16x8 pa[2];
#pragma unroll
    for (int mi = 0; mi < 2; ++mi)
      pa[mi] = *reinterpret_cast<const bf16x8*>(&pl[mi * 16 + li][lg * 8]);

    // V^T fragments: contiguous 16B loads thanks to [B,H,D,T] layout
    bf16x8 bv[4];
#pragma unroll
    for (int ni = 0; ni < 4; ++ni)
      bv[ni] = *reinterpret_cast<const bf16x8*>(Vh + (size_t)(ni * 16 + li) * Tt + s0 + lg * 8);

#pragma unroll
    for (int mi = 0; mi < 2; ++mi)
#pragma unroll
      for (int ni = 0; ni < 4; ++ni)
        o[mi][ni] = __builtin_amdgcn_mfma_f32_16x16x32_bf16(pa[mi], bv[ni], o[mi][ni], 0, 0, 0);
  }

  // epilogue: divide by softmax denom, write [B,T,H*D] bf16
  const int b = bh >> 4, h = bh & 15;
#pragma unroll
  for (int mi = 0; mi < 2; ++mi)
#pragma unroll
    for (int r = 0; r < 4; ++r) {
      const float inv = 1.f / lrun[mi][r];
      const int t = qr0 + mi * 16 + lg * 4 + r;
#pragma unroll
      for (int ni = 0; ni < 4; ++ni) {
        const int c = h * Dd + ni * 16 + li;
        O[((size_t)b * Tt + t) * Cc + c] = (bf16)(o[mi][ni][r] * inv);
      }
    }
}

// ---------------------------------------------------------------------------
extern "C" void kernel_launch(void* const* d_in, const int* in_sizes, int n_in,
                              void* d_out, int out_size, void* d_ws, size_t ws_size,
                              hipStream_t stream) {
  const float* x  = (const float*)d_in[0];
  const float* Wq = (const float*)d_in[1];
  const float* Wk = (const float*)d_in[2];
  const float* Wv = (const float*)d_in[3];
  const float* Wp = (const float*)d_in[4];
  const float* bp = (const float*)d_in[5];
  float* out = (float*)d_out;

  char* ws = (char*)d_ws;
  size_t off = 0;
  auto grab = [&](size_t bytes) { char* p = ws + off; off += (bytes + 255) & ~(size_t)255; return p; };

  bf16* xb    = (bf16*)grab((size_t)Mtot * Ktot * 2);   // x in bf16            8 MiB
  bf16* wqt   = (bf16*)grab((size_t)Ntot * Ktot * 2);   // Wq^T per-head        2 MiB
  bf16* wkt   = (bf16*)grab((size_t)Ntot * Ktot * 2);
  bf16* wvt   = (bf16*)grab((size_t)Ntot * Ktot * 2);
  bf16* wpt   = (bf16*)grab((size_t)Ntot * Ktot * 2);   // Wproj^T
  bf16* qb    = (bf16*)grab((size_t)Bb * Hh * Tt * Dd * 2);  // [B,H,T,D]       8 MiB
  bf16* kb    = (bf16*)grab((size_t)Bb * Hh * Tt * Dd * 2);
  bf16* vtb   = (bf16*)grab((size_t)Bb * Hh * Dd * Tt * 2);  // [B,H,D,T]
  bf16* attnb = (bf16*)grab((size_t)Mtot * Ntot * 2);        // [B,T,H*D]
  (void)ws_size;  // total ≈ 50 MiB

  const int nx = Mtot * Ktot;
  cvt_f32_bf16<<<nx / (256 * 4), 256, 0, stream>>>(x, xb, nx);

  // Wq/Wk/Wv: per-head [C][D] -> [D][C];  Wproj: [1024][1024] -> transposed
  transpose_cvt<<<dim3(2, 32, 16), dim3(32, 8), 0, stream>>>(Wq, wqt, Cc, Dd);
  transpose_cvt<<<dim3(2, 32, 16), dim3(32, 8), 0, stream>>>(Wk, wkt, Cc, Dd);
  transpose_cvt<<<dim3(2, 32, 16), dim3(32, 8), 0, stream>>>(Wv, wvt, Cc, Dd);
  transpose_cvt<<<dim3(32, 32, 1), dim3(32, 8), 0, stream>>>(Wp, wpt, Ntot, Cc);

  qkv_gemm<<<dim3(Ntot / 128, Mtot / 128, 3), 256, 0, stream>>>(xb, wqt, wkt, wvt, qb, kb, vtb);
  attn_kernel<<<dim3(Tt / 128, Bb * Hh), 256, 0, stream>>>(qb, kb, vtb, attnb);
  proj_gemm<<<dim3(Ntot / 128, Mtot / 128), 256, 0, stream>>>(attnb, wpt, out, bp);
}

// Round 2
// 163.845 us; speedup vs baseline: 1.3904x; 1.3904x over previous
//
#include <hip/hip_runtime.h>
#include <cstdint>
#include <cstddef>

// ---------------------------------------------------------------------------
// MultiHeadAttention: B=2 T=2048 C=1024 H=16 D=64, fp32 in/out, bf16 compute.
// cvt(x) -> transpose-cvt(W*) -> QKV GEMM (m97-style, scale folded into Q)
// -> flash attention (swapped-QK 32x32 MFMA, in-register softmax, defer-max)
// -> proj GEMM + bias.
// ---------------------------------------------------------------------------

typedef __bf16 bf16;
typedef __attribute__((ext_vector_type(2))) __bf16 bf16x2;
typedef __attribute__((ext_vector_type(4))) __bf16 bf16x4;
typedef __attribute__((ext_vector_type(8))) __bf16 bf16x8;
typedef __attribute__((ext_vector_type(4))) float f32x4;
typedef __attribute__((ext_vector_type(16))) float f32x16;
typedef __attribute__((ext_vector_type(4))) uint32_t u32x4;

#define AS1 __attribute__((address_space(1)))
#define AS3 __attribute__((address_space(3)))
typedef const AS1 void* gptr_t;
typedef AS3 void* lptr_t;

static constexpr int Bb = 2, Tt = 2048, Cc = 1024, Hh = 16, Dd = 64;
static constexpr int Mtot = Bb * Tt;   // 4096
static constexpr int Ktot = Cc;        // 1024
static constexpr int Ntot = Hh * Dd;   // 1024

// ---------------- fp32 -> bf16 elementwise convert -------------------------
__global__ void cvt_f32_bf16(const float* __restrict__ in, bf16* __restrict__ out, int n) {
  int i = (blockIdx.x * blockDim.x + threadIdx.x) * 4;
  if (i >= n) return;
  const float4 v = *reinterpret_cast<const float4*>(in + i);
  bf16x4 o;
  o[0] = (bf16)v.x; o[1] = (bf16)v.y; o[2] = (bf16)v.z; o[3] = (bf16)v.w;
  *reinterpret_cast<bf16x4*>(out + i) = o;
}

// ------------- batched [R][S] f32 -> [S][R] bf16 transpose -----------------
__global__ void transpose_cvt(const float* __restrict__ in, bf16* __restrict__ out,
                              int R, int S) {
  __shared__ float tile[32][33];
  const int batch = blockIdx.z;
  in  += (size_t)batch * R * S;
  out += (size_t)batch * R * S;
  const int r0 = blockIdx.y * 32, s0 = blockIdx.x * 32;
  const int tx = threadIdx.x, ty = threadIdx.y;   // 32 x 8
#pragma unroll
  for (int i = 0; i < 32; i += 8) {
    int r = r0 + ty + i, s = s0 + tx;
    tile[ty + i][tx] = (r < R && s < S) ? in[(size_t)r * S + s] : 0.f;
  }
  __syncthreads();
#pragma unroll
  for (int i = 0; i < 32; i += 8) {
    int s = s0 + ty + i, r = r0 + tx;
    if (s < S && r < R) out[(size_t)s * R + r] = (bf16)tile[tx][ty + i];
  }
}

// ---------------- 128x128 GEMM mainloop (m97 structure) --------------------
__device__ __forceinline__ void gemm_core_128(const bf16* __restrict__ A,
                                              const bf16* __restrict__ Bt,
                                              int m0, int n0, f32x4 acc[4][4]) {
  __shared__ __align__(16) char AsB[128 * 64 * 2];
  __shared__ __align__(16) char BsB[128 * 64 * 2];
  const int tid  = threadIdx.x;
  const int lane = tid & 63;
  const int w    = tid >> 6;
  const int li   = lane & 15, lg = lane >> 4;
  const int wr   = (w >> 1) * 64, wc = (w & 1) * 64;

  for (int kt = 0; kt < Ktot / 64; ++kt) {
    if (kt) __syncthreads();
#pragma unroll
    for (int it = 0; it < 4; ++it) {
      const int c   = it * 256 + tid;
      const int row = c >> 3, j = c & 7;
      const int jsw = j ^ (row & 7);
      const bf16* ga = A  + (size_t)(m0 + row) * Ktot + kt * 64 + jsw * 8;
      const bf16* gb = Bt + (size_t)(n0 + row) * Ktot + kt * 64 + jsw * 8;
      __builtin_amdgcn_global_load_lds(gptr_t(ga), lptr_t(AsB + (it * 256 + w * 64) * 16), 16, 0, 0);
      __builtin_amdgcn_global_load_lds(gptr_t(gb), lptr_t(BsB + (it * 256 + w * 64) * 16), 16, 0, 0);
    }
    __syncthreads();
#pragma unroll
    for (int kk = 0; kk < 2; ++kk) {
      bf16x8 af[4], bfv[4];
#pragma unroll
      for (int mi = 0; mi < 4; ++mi) {
        const int row = wr + mi * 16 + li;
        const int jj  = (kk * 4 + lg) ^ (row & 7);
        af[mi] = *reinterpret_cast<const bf16x8*>(AsB + row * 128 + jj * 16);
      }
#pragma unroll
      for (int ni = 0; ni < 4; ++ni) {
        const int row = wc + ni * 16 + li;
        const int jj  = (kk * 4 + lg) ^ (row & 7);
        bfv[ni] = *reinterpret_cast<const bf16x8*>(BsB + row * 128 + jj * 16);
      }
#pragma unroll
      for (int mi = 0; mi < 4; ++mi)
#pragma unroll
        for (int ni = 0; ni < 4; ++ni)
          acc[mi][ni] = __builtin_amdgcn_mfma_f32_16x16x32_bf16(af[mi], bfv[ni], acc[mi][ni], 0, 0, 0);
    }
  }
}

// ---------------- QKV projection GEMM --------------------------------------
// z=0 -> q [B,H,T,D] scaled by 1/sqrt(D)*log2(e); z=1 -> k; z=2 -> v^T [B,H,D,T]
__global__ __launch_bounds__(256) void qkv_gemm(const bf16* __restrict__ xb,
    const bf16* __restrict__ wqt, const bf16* __restrict__ wkt, const bf16* __restrict__ wvt,
    bf16* __restrict__ q, bf16* __restrict__ k, bf16* __restrict__ vt) {
  const int m0 = blockIdx.y * 128, n0 = blockIdx.x * 128;
  const int z  = blockIdx.z;
  const bf16* Bt = (z == 0) ? wqt : (z == 1) ? wkt : wvt;
  bf16* outp     = (z == 0) ? q   : (z == 1) ? k   : vt;
  const float scl = (z == 0) ? 0.18033688011112042f : 1.0f;  // (1/8)*log2(e)

  f32x4 acc[4][4];
#pragma unroll
  for (int mi = 0; mi < 4; ++mi)
#pragma unroll
    for (int ni = 0; ni < 4; ++ni) acc[mi][ni] = f32x4{0.f, 0.f, 0.f, 0.f};

  gemm_core_128(xb, Bt, m0, n0, acc);

  const int lane = threadIdx.x & 63, w = threadIdx.x >> 6;
  const int li = lane & 15, lg = lane >> 4;
  const int wr = (w >> 1) * 64, wc = (w & 1) * 64;
#pragma unroll
  for (int mi = 0; mi < 4; ++mi)
#pragma unroll
    for (int ni = 0; ni < 4; ++ni)
#pragma unroll
      for (int r = 0; r < 4; ++r) {
        const int mm = m0 + wr + mi * 16 + lg * 4 + r;   // b*T + t
        const int nn = n0 + wc + ni * 16 + li;           // h*64 + d
        const int b = mm >> 11, tt = mm & 2047;
        const int hd = nn >> 6, d = nn & 63;
        const float v = acc[mi][ni][r] * scl;
        if (z < 2) outp[(((size_t)(b * Hh + hd)) * Tt + tt) * Dd + d] = (bf16)v;
        else       outp[(((size_t)(b * Hh + hd)) * Dd + d) * Tt + tt] = (bf16)v;
      }
}

// ---------------- output projection GEMM (+bias, f32 out) ------------------
__global__ __launch_bounds__(256) void proj_gemm(const bf16* __restrict__ attnb,
    const bf16* __restrict__ wpt, float* __restrict__ out, const float* __restrict__ bias) {
  const int m0 = blockIdx.y * 128, n0 = blockIdx.x * 128;
  f32x4 acc[4][4];
#pragma unroll
  for (int mi = 0; mi < 4; ++mi)
#pragma unroll
    for (int ni = 0; ni < 4; ++ni) acc[mi][ni] = f32x4{0.f, 0.f, 0.f, 0.f};

  gemm_core_128(attnb, wpt, m0, n0, acc);

  const int lane = threadIdx.x & 63, w = threadIdx.x >> 6;
  const int li = lane & 15, lg = lane >> 4;
  const int wr = (w >> 1) * 64, wc = (w & 1) * 64;
#pragma unroll
  for (int mi = 0; mi < 4; ++mi)
#pragma unroll
    for (int ni = 0; ni < 4; ++ni)
#pragma unroll
      for (int r = 0; r < 4; ++r) {
        const int mm = m0 + wr + mi * 16 + lg * 4 + r;
        const int nn = n0 + wc + ni * 16 + li;
        out[(size_t)mm * Ntot + nn] = acc[mi][ni][r] + bias[nn];
      }
}

// ---------------- flash attention (swapped-QK, in-register softmax) --------
__device__ __forceinline__ uint32_t pk(float a, float b) {
  bf16x2 t; t[0] = (bf16)a; t[1] = (bf16)b;
  return __builtin_bit_cast(uint32_t, t);
}
__device__ __forceinline__ bf16x8 mk8(uint32_t w0, uint32_t w1, uint32_t w2, uint32_t w3) {
  u32x4 u = {w0, w1, w2, w3};
  return __builtin_bit_cast(bf16x8, u);
}

// One wave per (bh, 32-row q-tile). S^T = mfma(K,Q): lane holds q=lane&31,
// 32 s-values in regs (row=(c&3)+8*(c>>2)+4*(lane>>5) per tile of 32).
// Softmax fully in-register; one cross-half shfl per reduce; defer-max THR=8.
__global__ __launch_bounds__(256, 2) void attn_kernel(const bf16* __restrict__ Q,
    const bf16* __restrict__ K, const bf16* __restrict__ Vt, bf16* __restrict__ O) {
  const int tid = threadIdx.x, lane = tid & 63, w = tid >> 6;
  const int x = lane & 31, h = lane >> 5;
  const int g  = blockIdx.x * 4 + w;
  const int jt = 63 - (g >> 5);          // q-tile idx, heavy first
  const int bh = g & 31;
  const int qr0 = jt * 32;
  const int b = bh >> 4, hh = bh & 15;

  const bf16* Qh = Q  + (size_t)bh * Tt * Dd;
  const bf16* Kh = K  + (size_t)bh * Tt * Dd;
  const bf16* Vh = Vt + (size_t)bh * Dd * Tt;

  __shared__ float bc[4][32];            // per-wave row broadcast buffer

  // Q B-frags (scale pre-folded at projection): Q[qr0+x][ks*16+h*8+..]
  bf16x8 qf[4];
#pragma unroll
  for (int ks = 0; ks < 4; ++ks)
    qf[ks] = *reinterpret_cast<const bf16x8*>(Qh + (size_t)(qr0 + x) * Dd + ks * 16 + h * 8);

  f32x16 oc[2];
#pragma unroll
  for (int ns = 0; ns < 2; ++ns)
#pragma unroll
    for (int c = 0; c < 16; ++c) oc[ns][c] = 0.f;

  float m = -1e30f, l = 0.f;
  const int nsteps = (qr0 >> 6) + 1;

  // K A-frags for step 0: K[32t+x][ks*16+h*8+..]
  bf16x8 kf[2][4];
#pragma unroll
  for (int t = 0; t < 2; ++t)
#pragma unroll
    for (int ks = 0; ks < 4; ++ks)
      kf[t][ks] = *reinterpret_cast<const bf16x8*>(Kh + (size_t)(32 * t + x) * Dd + ks * 16 + h * 8);

  for (int st = 0; st < nsteps; ++st) {
    const int s0 = st * 64;
    const bool last = (st == nsteps - 1);

    // V B-frags for this step, issued early (hidden under QK + softmax)
    bf16x8 vf[2][4];
#pragma unroll
    for (int ns = 0; ns < 2; ++ns)
#pragma unroll
      for (int ks = 0; ks < 4; ++ks)
        vf[ns][ks] = *reinterpret_cast<const bf16x8*>(Vh + (size_t)(ns * 32 + x) * Tt + s0 + ks * 16 + h * 8);

    // S^T = K x Q^T  (already in log2 domain)
    f32x16 p[2];
#pragma unroll
    for (int t = 0; t < 2; ++t) {
#pragma unroll
      for (int c = 0; c < 16; ++c) p[t][c] = 0.f;
#pragma unroll
      for (int ks = 0; ks < 4; ++ks)
        p[t] = __builtin_amdgcn_mfma_f32_32x32x16_bf16(kf[t][ks], qf[ks], p[t], 0, 0, 0);
    }

    if (!last) {
      // prefetch next step's K into kf (dead after QK); hides L2 latency
#pragma unroll
      for (int t = 0; t < 2; ++t)
#pragma unroll
        for (int ks = 0; ks < 4; ++ks)
          kf[t][ks] = *reinterpret_cast<const bf16x8*>(Kh + (size_t)(s0 + 64 + 32 * t + x) * Dd + ks * 16 + h * 8);
    } else {
      // causal mask on diagonal step (covers both tile parities)
#pragma unroll
      for (int t = 0; t < 2; ++t)
#pragma unroll
        for (int c = 0; c < 16; ++c) {
          const int s = s0 + 32 * t + (c & 3) + 8 * (c >> 2) + 4 * h;
          if (s > qr0 + x) p[t][c] = -1e30f;
        }
    }

    // in-register row max (tree) + one cross-half shfl
    float mx[16];
#pragma unroll
    for (int i = 0; i < 16; ++i) mx[i] = fmaxf(p[0][i], p[1][i]);
#pragma unroll
    for (int srd = 8; srd >= 1; srd >>= 1)
#pragma unroll
      for (int i = 0; i < srd; ++i) mx[i] = fmaxf(mx[i], mx[i + srd]);
    const float pmax = fmaxf(mx[0], __shfl_xor(mx[0], 32, 64));

    // defer-max (T13): rescale O only when max grew by > 8 (log2 domain)
    if (!__all(pmax - m <= 8.f)) {
      const float mn  = fmaxf(m, pmax);
      const float fac = __builtin_amdgcn_exp2f(m - mn);
      l *= fac; m = mn;
      if (h == 0) bc[w][x] = fac;
#pragma unroll
      for (int c = 0; c < 16; ++c) {
        const float fr = bc[w][(c & 3) + 8 * (c >> 2) + 4 * h];
        oc[0][c] *= fr; oc[1][c] *= fr;
      }
    }

    // P = exp2(S - m); row sum (tree) + one cross-half shfl
#pragma unroll
    for (int t = 0; t < 2; ++t)
#pragma unroll
      for (int c = 0; c < 16; ++c) p[t][c] = __builtin_amdgcn_exp2f(p[t][c] - m);

    float sm[16];
#pragma unroll
    for (int i = 0; i < 16; ++i) sm[i] = p[0][i] + p[1][i];
#pragma unroll
    for (int srd = 8; srd >= 1; srd >>= 1)
#pragma unroll
      for (int i = 0; i < srd; ++i) sm[i] += sm[i + srd];
    l += sm[0] + __shfl_xor(sm[0], 32, 64);

    // pack P to bf16 A-frags: 16 packs + 8 cross-half shfl + selects
    bf16x8 pa[4];
#pragma unroll
    for (int t = 0; t < 2; ++t) {
      uint32_t dw[8];
#pragma unroll
      for (int i = 0; i < 8; ++i) dw[i] = pk(p[t][2 * i], p[t][2 * i + 1]);
      const uint32_t rA = (uint32_t)__shfl_xor((int)(h ? dw[0] : dw[2]), 32, 64);
      const uint32_t rB = (uint32_t)__shfl_xor((int)(h ? dw[1] : dw[3]), 32, 64);
      const uint32_t rC = (uint32_t)__shfl_xor((int)(h ? dw[4] : dw[6]), 32, 64);
      const uint32_t rD = (uint32_t)__shfl_xor((int)(h ? dw[5] : dw[7]), 32, 64);
      pa[2 * t]     = mk8(h ? rA : dw[0], h ? rB : dw[1], h ? dw[2] : rA, h ? dw[3] : rB);
      pa[2 * t + 1] = mk8(h ? rC : dw[4], h ? rD : dw[5], h ? dw[6] : rC, h ? dw[7] : rD);
    }

    // O += P x V
#pragma unroll
    for (int ns = 0; ns < 2; ++ns)
#pragma unroll
      for (int ks = 0; ks < 4; ++ks)
        oc[ns] = __builtin_amdgcn_mfma_f32_32x32x16_bf16(pa[ks], vf[ns][ks], oc[ns], 0, 0, 0);
  }

  // epilogue: O[q][d] / l[q]  (O rows in C/D layout -> broadcast 1/l via LDS)
  if (h == 0) bc[w][x] = 1.f / l;
#pragma unroll
  for (int c = 0; c < 16; ++c) {
    const int q = (c & 3) + 8 * (c >> 2) + 4 * h;
    const float inv = bc[w][q];
    const int trow = qr0 + q;
#pragma unroll
    for (int ns = 0; ns < 2; ++ns)
      O[((size_t)b * Tt + trow) * Cc + hh * Dd + ns * 32 + x] = (bf16)(oc[ns][c] * inv);
  }
}

// ---------------------------------------------------------------------------
extern "C" void kernel_launch(void* const* d_in, const int* in_sizes, int n_in,
                              void* d_out, int out_size, void* d_ws, size_t ws_size,
                              hipStream_t stream) {
  const float* x  = (const float*)d_in[0];
  const float* Wq = (const float*)d_in[1];
  const float* Wk = (const float*)d_in[2];
  const float* Wv = (const float*)d_in[3];
  const float* Wp = (const float*)d_in[4];
  const float* bp = (const float*)d_in[5];
  float* out = (float*)d_out;

  char* ws = (char*)d_ws;
  size_t off = 0;
  auto grab = [&](size_t bytes) { char* p = ws + off; off += (bytes + 255) & ~(size_t)255; return p; };

  bf16* xb    = (bf16*)grab((size_t)Mtot * Ktot * 2);
  bf16* wqt   = (bf16*)grab((size_t)Ntot * Ktot * 2);
  bf16* wkt   = (bf16*)grab((size_t)Ntot * Ktot * 2);
  bf16* wvt   = (bf16*)grab((size_t)Ntot * Ktot * 2);
  bf16* wpt   = (bf16*)grab((size_t)Ntot * Ktot * 2);
  bf16* qb    = (bf16*)grab((size_t)Bb * Hh * Tt * Dd * 2);  // [B,H,T,D]
  bf16* kb    = (bf16*)grab((size_t)Bb * Hh * Tt * Dd * 2);
  bf16* vtb   = (bf16*)grab((size_t)Bb * Hh * Dd * Tt * 2);  // [B,H,D,T]
  bf16* attnb = (bf16*)grab((size_t)Mtot * Ntot * 2);        // [B,T,H*D]
  (void)ws_size;

  const int nx = Mtot * Ktot;
  cvt_f32_bf16<<<nx / (256 * 4), 256, 0, stream>>>(x, xb, nx);

  transpose_cvt<<<dim3(2, 32, 16), dim3(32, 8), 0, stream>>>(Wq, wqt, Cc, Dd);
  transpose_cvt<<<dim3(2, 32, 16), dim3(32, 8), 0, stream>>>(Wk, wkt, Cc, Dd);
  transpose_cvt<<<dim3(2, 32, 16), dim3(32, 8), 0, stream>>>(Wv, wvt, Cc, Dd);
  transpose_cvt<<<dim3(32, 32, 1), dim3(32, 8), 0, stream>>>(Wp, wpt, Ntot, Cc);

  qkv_gemm<<<dim3(Ntot / 128, Mtot / 128, 3), 256, 0, stream>>>(xb, wqt, wkt, wvt, qb, kb, vtb);
  attn_kernel<<<dim3(512), 256, 0, stream>>>(qb, kb, vtb, attnb);
  proj_gemm<<<dim3(Ntot / 128, Mtot / 128), 256, 0, stream>>>(attnb, wpt, out, bp);
}